// Round 1
// baseline (442.866 us; speedup 1.0000x reference)
//
#include <hip/hip_runtime.h>
#include <math.h>

#define DIM 1280
#define NDIM 8
#define CHUNKS 5   // 5 chunks * 64 lanes * 4 floats = 1280

__global__ __launch_bounds__(256, 2)
void fsq_kernel(const float* __restrict__ x, const float* __restrict__ W,
                const float* __restrict__ b, int* __restrict__ out, int n_tok) {
    const int lane    = threadIdx.x & 63;
    const int wave    = (int)((blockIdx.x * blockDim.x + threadIdx.x) >> 6);
    const int n_waves = (int)((gridDim.x * blockDim.x) >> 6);

    // digit = +1 iff tanh(h)*SCALE > 0.5  <=>  h > atanh(0.5/SCALE) (tanh monotone;
    // exact 0.5 rounds to 0 under round-half-even, matched by strict >).
    const float T = (float)atanh(0.5 / 0.9990000128746033);

    // Preload W fragments into registers: w[c][k] = W[k][c*256 + lane*4 .. +3]
    float4 w[CHUNKS][NDIM];
    #pragma unroll
    for (int c = 0; c < CHUNKS; ++c) {
        #pragma unroll
        for (int k = 0; k < NDIM; ++k) {
            w[c][k] = *(const float4*)(W + k * DIM + c * 256 + lane * 4);
        }
    }

    float bias[NDIM];
    #pragma unroll
    for (int k = 0; k < NDIM; ++k) bias[k] = b[k];

    for (int t = wave; t < n_tok; t += n_waves) {
        const float4* xp = (const float4*)(x + (size_t)t * DIM);
        float4 xv[CHUNKS];
        #pragma unroll
        for (int c = 0; c < CHUNKS; ++c) xv[c] = xp[c * 64 + lane];

        float acc[NDIM];
        #pragma unroll
        for (int k = 0; k < NDIM; ++k) acc[k] = 0.0f;

        #pragma unroll
        for (int c = 0; c < CHUNKS; ++c) {
            #pragma unroll
            for (int k = 0; k < NDIM; ++k) {
                acc[k] = fmaf(xv[c].x, w[c][k].x, acc[k]);
                acc[k] = fmaf(xv[c].y, w[c][k].y, acc[k]);
                acc[k] = fmaf(xv[c].z, w[c][k].z, acc[k]);
                acc[k] = fmaf(xv[c].w, w[c][k].w, acc[k]);
            }
        }

        // Butterfly-reduce each of the 8 dots across the 64-lane wave.
        #pragma unroll
        for (int k = 0; k < NDIM; ++k) {
            #pragma unroll
            for (int off = 32; off >= 1; off >>= 1) {
                acc[k] += __shfl_xor(acc[k], off, 64);
            }
        }

        int mu = 0, p3 = 1;
        #pragma unroll
        for (int k = 0; k < NDIM; ++k) {
            float h = acc[k] + bias[k];
            int d = 1 + (h > T ? 1 : 0) - (h < -T ? 1 : 0);  // {0,1,2}
            mu += d * p3;
            p3 *= 3;
        }
        if (lane == 0) out[t] = mu;
    }
}

extern "C" void kernel_launch(void* const* d_in, const int* in_sizes, int n_in,
                              void* d_out, int out_size, void* d_ws, size_t ws_size,
                              hipStream_t stream) {
    const float* x = (const float*)d_in[0];   // (B*T, 1280) fp32
    const float* W = (const float*)d_in[1];   // (8, 1280) fp32
    const float* b = (const float*)d_in[2];   // (8,) fp32
    int* out = (int*)d_out;                   // (B*T,) int32

    const int n_tok = in_sizes[0] / DIM;      // 65536
    const int blocks = 2048;                  // 8192 waves -> 8 tokens/wave
    fsq_kernel<<<blocks, 256, 0, stream>>>(x, W, b, out, n_tok);
}